// Round 1
// baseline (311.255 us; speedup 1.0000x reference)
//
#include <hip/hip_runtime.h>
#include <hip/hip_bf16.h>
#include <cstdint>
#include <math.h>

// ---------------------------------------------------------------------------
// MyMultiHeadAttention: q/k/v proj (bf16 MFMA GEMM) -> fused flash attention
// (exact -1e9 finite-mask semantics) -> output proj (f32 out).
// B=8 S=1024 D=1024 H=16 Dh=64.
// ---------------------------------------------------------------------------

typedef __bf16 bf16_t;
typedef __bf16 bf16x8 __attribute__((ext_vector_type(8)));
typedef float  f32x4  __attribute__((ext_vector_type(4)));

#define MFMA16(a, b, c) __builtin_amdgcn_mfma_f32_16x16x32_bf16((a), (b), (c), 0, 0, 0)
#define NEGV (-1e9f)

__device__ __forceinline__ void gl_lds16(const void* gp, void* lp) {
  __builtin_amdgcn_global_load_lds(
      (__attribute__((address_space(1))) void*)(gp),
      (__attribute__((address_space(3))) void*)(lp), 16, 0, 0);
}

// ---------------- f32 -> bf16 bulk convert (8 elems/thread) ----------------
__global__ __launch_bounds__(256) void cvt_f32_bf16(const float* __restrict__ in,
                                                    bf16_t* __restrict__ out, int n8) {
  int i = blockIdx.x * 256 + threadIdx.x;
  if (i < n8) {
    const float4* p = reinterpret_cast<const float4*>(in) + (size_t)i * 2;
    float4 a = p[0], b = p[1];
    bf16x8 r = {(bf16_t)a.x, (bf16_t)a.y, (bf16_t)a.z, (bf16_t)a.w,
                (bf16_t)b.x, (bf16_t)b.y, (bf16_t)b.z, (bf16_t)b.w};
    *reinterpret_cast<bf16x8*>(out + (size_t)i * 8) = r;
  }
}

// ---------------- GEMM: C[m,n] = sum_k A[m,k]*W[n,k] (+bias) ----------------
// A: [M,K] bf16 row-major.  W: [N,K] bf16 row-major (torch Linear weight).
// MODE 0: out bf16 [M,N].  MODE 1: out bf16 v-transposed vt[b,h,d,s] (S=1024,
// H=16, Dh=64).  MODE 2: out f32 [M,N].
// 128x128 tile, BK=32, 256 thr (4 waves, each 64x64 via 4x4 16x16x32 MFMA).
template <int MODE, bool BIAS>
__global__ __launch_bounds__(256) void gemm_bt(const bf16_t* __restrict__ A,
                                               const bf16_t* __restrict__ W,
                                               const float* __restrict__ bias,
                                               void* __restrict__ outp,
                                               int M, int N, int K) {
  __shared__ bf16_t As[128 * 32];
  __shared__ bf16_t Bs[128 * 32];
  const int t = threadIdx.x;
  const int w = t >> 6, l = t & 63, lr = l & 15, lg = l >> 4;
  const int m0 = blockIdx.y * 128, n0 = blockIdx.x * 128;
  const int wm = (w >> 1) * 64, wn = (w & 1) * 64;

  f32x4 acc[4][4] = {};
  const bf16_t* Ag = A + (size_t)(m0 + (t >> 2)) * K + (t & 3) * 8;
  const bf16_t* Wg = W + (size_t)(n0 + (t >> 2)) * K + (t & 3) * 8;
  char* AsB = (char*)As;
  char* BsB = (char*)Bs;

  for (int kt = 0; kt < K; kt += 32) {
    gl_lds16(Ag + kt,                    AsB + t * 16);
    gl_lds16(Ag + kt + (size_t)64 * K,   AsB + 4096 + t * 16);
    gl_lds16(Wg + kt,                    BsB + t * 16);
    gl_lds16(Wg + kt + (size_t)64 * K,   BsB + 4096 + t * 16);
    asm volatile("s_waitcnt vmcnt(0)");
    __syncthreads();

    bf16x8 af[4], bfr[4];
#pragma unroll
    for (int mt = 0; mt < 4; mt++)
      af[mt] = *reinterpret_cast<const bf16x8*>(AsB + ((wm + mt * 16 + lr) * 32 + lg * 8) * 2);
#pragma unroll
    for (int nt = 0; nt < 4; nt++)
      bfr[nt] = *reinterpret_cast<const bf16x8*>(BsB + ((wn + nt * 16 + lr) * 32 + lg * 8) * 2);
#pragma unroll
    for (int mt = 0; mt < 4; mt++)
#pragma unroll
      for (int nt = 0; nt < 4; nt++)
        acc[mt][nt] = MFMA16(af[mt], bfr[nt], acc[mt][nt]);
    __syncthreads();
  }

#pragma unroll
  for (int nt = 0; nt < 4; nt++) {
    const int col = n0 + wn + nt * 16 + lr;
    const float bb = BIAS ? bias[col] : 0.0f;
#pragma unroll
    for (int mt = 0; mt < 4; mt++) {
#pragma unroll
      for (int i = 0; i < 4; i++) {
        const int row = m0 + wm + mt * 16 + lg * 4 + i;
        const float v = acc[mt][nt][i] + bb;
        if (MODE == 2) {
          ((float*)outp)[(size_t)row * N + col] = v;
        } else if (MODE == 0) {
          ((bf16_t*)outp)[(size_t)row * N + col] = (bf16_t)v;
        } else {  // vt[( (b*16+h)*64 + d )*1024 + s]
          const int b = row >> 10, s = row & 1023;
          const int h = col >> 6, d = col & 63;
          ((bf16_t*)outp)[(size_t)((b * 16 + h) * 64 + d) * 1024 + s] = (bf16_t)v;
        }
      }
    }
  }
}

// ---------------- fused flash attention ----------------
// grid: x = S/64 q-tiles, y = B*H.  256 thr = 4 waves, 16 q-rows/wave.
// qp,kp: bf16 [B,S,D] (head-major cols).  vt: bf16 [B*H, 64, S] (V^T per head).
// Exact reference mask semantics with finite -1e9 (no tile skipping).
__global__ __launch_bounds__(256) void attn_fused(const bf16_t* __restrict__ qp,
                                                  const bf16_t* __restrict__ kp,
                                                  const bf16_t* __restrict__ vt,
                                                  const int* __restrict__ pad,
                                                  bf16_t* __restrict__ outp) {
  __shared__ bf16_t Ks[64 * 64];        // [key][dh]
  __shared__ bf16_t Vts[64 * 64];       // [dh][key]
  __shared__ bf16_t Ps[4][16 * 64];     // per-wave P tile [q][key]
  const int t = threadIdx.x, w = t >> 6, l = t & 63, lr = l & 15, lg = l >> 4;
  const int bh = blockIdx.y, b = bh >> 4, h = bh & 15;
  const int q0 = blockIdx.x * 64;
  char* KsB = (char*)Ks;
  char* VtB = (char*)Vts;

  // Q fragments (A-operand rows = lr, k = lg*8 + j), held in regs for all k-tiles
  const bf16_t* qg = qp + (size_t)(b * 1024 + q0 + w * 16 + lr) * 1024 + h * 64 + lg * 8;
  const bf16x8 qa0 = *reinterpret_cast<const bf16x8*>(qg);
  const bf16x8 qa1 = *reinterpret_cast<const bf16x8*>(qg + 32);

  f32x4 o[4] = {};
  float m_[4] = {-INFINITY, -INFINITY, -INFINITY, -INFINITY};
  float ld_[4] = {};
  const int qrow_base = q0 + w * 16 + lg * 4;  // acc-layout rows

  for (int k0 = 0; k0 < 1024; k0 += 64) {
    const bf16_t* kg = kp + (size_t)(b * 1024 + k0 + (t >> 3)) * 1024 + h * 64 + (t & 7) * 8;
    gl_lds16(kg,                      KsB + t * 16);
    gl_lds16(kg + (size_t)32 * 1024,  KsB + 4096 + t * 16);
    const bf16_t* vg = vt + (size_t)(bh * 64 + (t >> 3)) * 1024 + k0 + (t & 7) * 8;
    gl_lds16(vg,                      VtB + t * 16);
    gl_lds16(vg + (size_t)32 * 1024,  VtB + 4096 + t * 16);
    asm volatile("s_waitcnt vmcnt(0)");
    __syncthreads();

    // scores: 16 q x 64 keys per wave
    f32x4 s[4] = {};
#pragma unroll
    for (int nt = 0; nt < 4; nt++) {
      bf16x8 kb0 = *reinterpret_cast<const bf16x8*>(KsB + ((nt * 16 + lr) * 64 + lg * 8) * 2);
      bf16x8 kb1 = *reinterpret_cast<const bf16x8*>(KsB + ((nt * 16 + lr) * 64 + 32 + lg * 8) * 2);
      s[nt] = MFMA16(qa0, kb0, s[nt]);
      s[nt] = MFMA16(qa1, kb1, s[nt]);
    }

    // masking — replicate reference f32 arithmetic exactly
#pragma unroll
    for (int nt = 0; nt < 4; nt++) {
      const int kc = k0 + nt * 16 + lr;
      const bool pd = pad[b * 1024 + kc] != 0;
#pragma unroll
      for (int i = 0; i < 4; i++) {
        float v = s[nt][i] * 0.125f;
        if (pd) v = NEGV;
        if (kc > qrow_base + i) v += NEGV;
        s[nt][i] = v;
      }
    }

    // online softmax update (row groups = 16 consecutive lanes)
    float scl[4];
#pragma unroll
    for (int i = 0; i < 4; i++) {
      float x = fmaxf(fmaxf(s[0][i], s[1][i]), fmaxf(s[2][i], s[3][i]));
#pragma unroll
      for (int d = 1; d < 16; d <<= 1) x = fmaxf(x, __shfl_xor(x, d, 64));
      const float mn = fmaxf(m_[i], x);
      scl[i] = __expf(m_[i] - mn);
      m_[i] = mn;
    }
#pragma unroll
    for (int i = 0; i < 4; i++) {
      float a = 0.0f;
#pragma unroll
      for (int nt = 0; nt < 4; nt++) {
        const float p = __expf(s[nt][i] - m_[i]);
        s[nt][i] = p;
        a += p;
      }
#pragma unroll
      for (int d = 1; d < 16; d <<= 1) a += __shfl_xor(a, d, 64);
      ld_[i] = ld_[i] * scl[i] + a;
      o[0][i] *= scl[i]; o[1][i] *= scl[i]; o[2][i] *= scl[i]; o[3][i] *= scl[i];
    }

    // P -> per-wave LDS (acc layout -> A-frag layout round-trip)
#pragma unroll
    for (int nt = 0; nt < 4; nt++)
#pragma unroll
      for (int i = 0; i < 4; i++)
        Ps[w][(lg * 4 + i) * 64 + nt * 16 + lr] = (bf16_t)s[nt][i];
    asm volatile("s_waitcnt lgkmcnt(0)");

    // PV: o[q, d] += P[q, k] * V[k, d]  (B-frag from V^T tile)
#pragma unroll
    for (int c = 0; c < 2; c++) {
      bf16x8 pf = *reinterpret_cast<const bf16x8*>((char*)&Ps[w][0] + (lr * 64 + c * 32 + lg * 8) * 2);
#pragma unroll
      for (int nt = 0; nt < 4; nt++) {
        bf16x8 vf = *reinterpret_cast<const bf16x8*>(VtB + ((nt * 16 + lr) * 64 + c * 32 + lg * 8) * 2);
        o[nt] = MFMA16(pf, vf, o[nt]);
      }
    }
    __syncthreads();
  }

  // epilogue: normalize and store bf16 [B,S,D]
#pragma unroll
  for (int nt = 0; nt < 4; nt++)
#pragma unroll
    for (int i = 0; i < 4; i++) {
      const float v = o[nt][i] / ld_[i];
      outp[(size_t)(b * 1024 + qrow_base + i) * 1024 + h * 64 + nt * 16 + lr] = (bf16_t)v;
    }
}

// ---------------------------------------------------------------------------
extern "C" void kernel_launch(void* const* d_in, const int* in_sizes, int n_in,
                              void* d_out, int out_size, void* d_ws, size_t ws_size,
                              hipStream_t stream) {
  const float* q   = (const float*)d_in[0];
  const float* k   = (const float*)d_in[1];
  const float* v   = (const float*)d_in[2];
  const int*   pad = (const int*)d_in[3];   // bernoulli bool -> int32 per harness
  // d_in[4] causal_mask: synthesized in-kernel (exact 0 / -1e9 values)
  const float* wq  = (const float*)d_in[5];
  const float* bq  = (const float*)d_in[6];
  const float* wk  = (const float*)d_in[7];
  const float* wv  = (const float*)d_in[8];
  const float* bv  = (const float*)d_in[9];
  const float* wo  = (const float*)d_in[10];
  const float* bo  = (const float*)d_in[11];

  const int M = 8192, N = 1024, K = 1024;
  const int nBig = M * N;       // 8,388,608
  const int nW   = N * K;       // 1,048,576

  char* ws = (char*)d_ws;
  const size_t MiB = 1024 * 1024;
  bf16_t* qbf = (bf16_t*)(ws + 0 * MiB);    // 16 MiB; reused as attnO later
  bf16_t* kbf = (bf16_t*)(ws + 16 * MiB);   // 16 MiB
  bf16_t* vbf = (bf16_t*)(ws + 32 * MiB);   // 16 MiB
  bf16_t* qp  = (bf16_t*)(ws + 48 * MiB);   // 16 MiB
  bf16_t* kp  = (bf16_t*)(ws + 64 * MiB);   // 16 MiB
  bf16_t* vtw = (bf16_t*)(ws + 80 * MiB);   // 16 MiB (V^T per head)
  bf16_t* wqb = (bf16_t*)(ws + 96 * MiB);   // 2 MiB
  bf16_t* wkb = (bf16_t*)(ws + 98 * MiB);   // 2 MiB
  bf16_t* wvb = (bf16_t*)(ws + 100 * MiB);  // 2 MiB
  bf16_t* wob = (bf16_t*)(ws + 102 * MiB);  // 2 MiB  => total 104 MiB
  bf16_t* attnO = qbf;  // alias: qbf dead after q-projection

  // converts
  cvt_f32_bf16<<<nBig / 2048, 256, 0, stream>>>(q, qbf, nBig / 8);
  cvt_f32_bf16<<<nBig / 2048, 256, 0, stream>>>(k, kbf, nBig / 8);
  cvt_f32_bf16<<<nBig / 2048, 256, 0, stream>>>(v, vbf, nBig / 8);
  cvt_f32_bf16<<<nW / 2048, 256, 0, stream>>>(wq, wqb, nW / 8);
  cvt_f32_bf16<<<nW / 2048, 256, 0, stream>>>(wk, wkb, nW / 8);
  cvt_f32_bf16<<<nW / 2048, 256, 0, stream>>>(wv, wvb, nW / 8);
  cvt_f32_bf16<<<nW / 2048, 256, 0, stream>>>(wo, wob, nW / 8);

  dim3 gg(N / 128, M / 128);  // (8, 64)
  gemm_bt<0, true ><<<gg, 256, 0, stream>>>(qbf, wqb, bq, qp,  M, N, K);
  gemm_bt<0, false><<<gg, 256, 0, stream>>>(kbf, wkb, nullptr, kp, M, N, K);
  gemm_bt<1, true ><<<gg, 256, 0, stream>>>(vbf, wvb, bv, vtw, M, N, K);

  attn_fused<<<dim3(16, 128), 256, 0, stream>>>(qp, kp, vtw, pad, attnO);

  gemm_bt<2, true ><<<gg, 256, 0, stream>>>(attnO, wob, bo, d_out, M, N, K);
}

// Round 2
// 274.992 us; speedup vs baseline: 1.1319x; 1.1319x over previous
//
#include <hip/hip_runtime.h>
#include <hip/hip_bf16.h>
#include <cstdint>
#include <math.h>

// ---------------------------------------------------------------------------
// MyMultiHeadAttention: q/k/v proj (bf16 MFMA GEMM) -> fused flash attention
// (exact -1e9 finite-mask semantics, swizzled LDS, dbuf K/V, tile skip)
// -> output proj (f32 out).  B=8 S=1024 D=1024 H=16 Dh=64.
// ---------------------------------------------------------------------------

typedef __bf16 bf16_t;
typedef __bf16 bf16x8 __attribute__((ext_vector_type(8)));
typedef float  f32x4  __attribute__((ext_vector_type(4)));

#define MFMA16(a, b, c) __builtin_amdgcn_mfma_f32_16x16x32_bf16((a), (b), (c), 0, 0, 0)
#define NEGV (-1e9f)

__device__ __forceinline__ void gl_lds16(const void* gp, void* lp) {
  __builtin_amdgcn_global_load_lds(
      (__attribute__((address_space(1))) void*)(gp),
      (__attribute__((address_space(3))) void*)(lp), 16, 0, 0);
}

// ---------------- f32 -> bf16 bulk converts (8 elems/thread) ----------------
__device__ __forceinline__ void cvt_body(const float* __restrict__ in,
                                         bf16_t* __restrict__ out, int i, int n8) {
  if (i < n8) {
    const float4* p = reinterpret_cast<const float4*>(in) + (size_t)i * 2;
    float4 a = p[0], b = p[1];
    bf16x8 r = {(bf16_t)a.x, (bf16_t)a.y, (bf16_t)a.z, (bf16_t)a.w,
                (bf16_t)b.x, (bf16_t)b.y, (bf16_t)b.z, (bf16_t)b.w};
    *reinterpret_cast<bf16x8*>(out + (size_t)i * 8) = r;
  }
}

__global__ __launch_bounds__(256) void cvt_qkv(const float* __restrict__ a, const float* __restrict__ b,
                                               const float* __restrict__ c,
                                               bf16_t* __restrict__ oa, bf16_t* __restrict__ ob,
                                               bf16_t* __restrict__ oc, int n8) {
  const float* in = blockIdx.y == 0 ? a : (blockIdx.y == 1 ? b : c);
  bf16_t* out     = blockIdx.y == 0 ? oa : (blockIdx.y == 1 ? ob : oc);
  cvt_body(in, out, blockIdx.x * 256 + threadIdx.x, n8);
}

__global__ __launch_bounds__(256) void cvt_w4(const float* __restrict__ a, const float* __restrict__ b,
                                              const float* __restrict__ c, const float* __restrict__ d,
                                              bf16_t* __restrict__ oa, bf16_t* __restrict__ ob,
                                              bf16_t* __restrict__ oc, bf16_t* __restrict__ od, int n8) {
  const float* in = blockIdx.y == 0 ? a : (blockIdx.y == 1 ? b : (blockIdx.y == 2 ? c : d));
  bf16_t* out     = blockIdx.y == 0 ? oa : (blockIdx.y == 1 ? ob : (blockIdx.y == 2 ? oc : od));
  cvt_body(in, out, blockIdx.x * 256 + threadIdx.x, n8);
}

// ---------------- GEMM: C[m,n] = sum_k A[m,k]*W[n,k] (+bias) ----------------
// MODE 0: out bf16 [M,N].  MODE 1: out bf16 vt[b,h,d,s].  MODE 2: out f32.
template <int MODE, bool BIAS>
__global__ __launch_bounds__(256) void gemm_bt(const bf16_t* __restrict__ A,
                                               const bf16_t* __restrict__ W,
                                               const float* __restrict__ bias,
                                               void* __restrict__ outp,
                                               int M, int N, int K) {
  __shared__ bf16_t As[128 * 32];
  __shared__ bf16_t Bs[128 * 32];
  const int t = threadIdx.x;
  const int w = t >> 6, l = t & 63, lr = l & 15, lg = l >> 4;
  const int m0 = blockIdx.y * 128, n0 = blockIdx.x * 128;
  const int wm = (w >> 1) * 64, wn = (w & 1) * 64;

  f32x4 acc[4][4] = {};
  const bf16_t* Ag = A + (size_t)(m0 + (t >> 2)) * K + (t & 3) * 8;
  const bf16_t* Wg = W + (size_t)(n0 + (t >> 2)) * K + (t & 3) * 8;
  char* AsB = (char*)As;
  char* BsB = (char*)Bs;

  for (int kt = 0; kt < K; kt += 32) {
    gl_lds16(Ag + kt,                    AsB + t * 16);
    gl_lds16(Ag + kt + (size_t)64 * K,   AsB + 4096 + t * 16);
    gl_lds16(Wg + kt,                    BsB + t * 16);
    gl_lds16(Wg + kt + (size_t)64 * K,   BsB + 4096 + t * 16);
    asm volatile("s_waitcnt vmcnt(0)");
    __syncthreads();

    bf16x8 af[4], bfr[4];
#pragma unroll
    for (int mt = 0; mt < 4; mt++)
      af[mt] = *reinterpret_cast<const bf16x8*>(AsB + ((wm + mt * 16 + lr) * 32 + lg * 8) * 2);
#pragma unroll
    for (int nt = 0; nt < 4; nt++)
      bfr[nt] = *reinterpret_cast<const bf16x8*>(BsB + ((wn + nt * 16 + lr) * 32 + lg * 8) * 2);
#pragma unroll
    for (int mt = 0; mt < 4; mt++)
#pragma unroll
      for (int nt = 0; nt < 4; nt++)
        acc[mt][nt] = MFMA16(af[mt], bfr[nt], acc[mt][nt]);
    __syncthreads();
  }

#pragma unroll
  for (int nt = 0; nt < 4; nt++) {
    const int col = n0 + wn + nt * 16 + lr;
    const float bb = BIAS ? bias[col] : 0.0f;
#pragma unroll
    for (int mt = 0; mt < 4; mt++) {
#pragma unroll
      for (int i = 0; i < 4; i++) {
        const int row = m0 + wm + mt * 16 + lg * 4 + i;
        const float v = acc[mt][nt][i] + bb;
        if (MODE == 2) {
          ((float*)outp)[(size_t)row * N + col] = v;
        } else if (MODE == 0) {
          ((bf16_t*)outp)[(size_t)row * N + col] = (bf16_t)v;
        } else {  // vt[( (b*16+h)*64 + d )*1024 + s]
          const int b = row >> 10, s = row & 1023;
          const int h = col >> 6, d = col & 63;
          ((bf16_t*)outp)[(size_t)((b * 16 + h) * 64 + d) * 1024 + s] = (bf16_t)v;
        }
      }
    }
  }
}

// ---------------- fused flash attention (swizzled + dbuf + skip) ----------------
// 1-D grid of 2048 blocks, bijective XCD swizzle. 256 thr = 4 waves, 16 q/wave.
// LDS tiles XOR-swizzled: logical (row, 16B-chunk c) stored at chunk c^(row&7);
// global_load_lds writes linearly, so the *source* address is pre-swizzled.
__global__ __launch_bounds__(256) void attn_fused(const bf16_t* __restrict__ qp,
                                                  const bf16_t* __restrict__ kp,
                                                  const bf16_t* __restrict__ vt,
                                                  const int* __restrict__ pad,
                                                  bf16_t* __restrict__ outp) {
  __shared__ bf16_t Ks[2][64 * 64];   // [key][dh], swizzled
  __shared__ bf16_t Vts[2][64 * 64];  // [dh][key], swizzled
  __shared__ bf16_t Ps[4][16 * 64];   // per-wave P [q][key], swizzled
  __shared__ int padI[1024];
  const int t = threadIdx.x, w = t >> 6, l = t & 63, lr = l & 15, lg = l >> 4;
  const int wg = (int)(blockIdx.x & 7) * 256 + (int)(blockIdx.x >> 3);  // XCD swizzle (2048%8==0)
  const int bh = wg >> 4, b = bh >> 4, h = bh & 15;
  const int q0 = (wg & 15) * 64;

  // staging geometry: lane t -> LDS row t>>3 (and +32), chunk t&7 (linear dest);
  // source chunk pre-swizzled so LDS[r][c] holds global chunk c^(r&7).
  const int srow = t >> 3, sc = t & 7;
  const int gc = sc ^ (srow & 7);
  const bf16_t* kgb = kp + (size_t)(b * 1024 + srow) * 1024 + h * 64 + gc * 8;
  const bf16_t* vgb = vt + (size_t)(bh * 64 + srow) * 1024 + gc * 8;

  auto stage = [&](int bufi, int k0s) {
    char* Kd = (char*)(Ks[bufi]);
    char* Vd = (char*)(Vts[bufi]);
    gl_lds16(kgb + (size_t)k0s * 1024,        Kd + t * 16);
    gl_lds16(kgb + (size_t)(k0s + 32) * 1024, Kd + 4096 + t * 16);
    gl_lds16(vgb + k0s,                       Vd + t * 16);
    gl_lds16(vgb + k0s + (size_t)32 * 1024,   Vd + 4096 + t * 16);
  };

  // Q fragments held in regs for all k-tiles
  const bf16_t* qg = qp + (size_t)(b * 1024 + q0 + w * 16 + lr) * 1024 + h * 64 + lg * 8;
  const bf16x8 qa0 = *reinterpret_cast<const bf16x8*>(qg);
  const bf16x8 qa1 = *reinterpret_cast<const bf16x8*>(qg + 32);

  f32x4 o[4] = {};
  float m_[4] = {-INFINITY, -INFINITY, -INFINITY, -INFINITY};
  float ld_[4] = {};
  const int qrow = q0 + w * 16 + lg * 4;

  // prologue: tile 0 + pad flags (5 outstanding loads)
  stage(0, 0);
  gl_lds16(pad + b * 1024 + t * 4, (char*)padI + t * 16);

  for (int kt = 0; kt < 16; ++kt) {
    const int cur = kt & 1;
    if (kt < 15) {
      stage(cur ^ 1, (kt + 1) * 64);                       // prefetch next tile
      asm volatile("s_waitcnt vmcnt(4)" ::: "memory");     // current tile's loads done
    } else {
      asm volatile("s_waitcnt vmcnt(0)" ::: "memory");
    }
    __builtin_amdgcn_s_barrier();

    const char* Kb = (const char*)(Ks[cur]);
    const char* Vb = (const char*)(Vts[cur]);
    const int k0 = kt * 64;

    // QK^T: 16 q x 64 keys per wave
    f32x4 s[4] = {};
#pragma unroll
    for (int nt = 0; nt < 4; nt++) {
      const int row = nt * 16 + lr;
      const int sw = (row & 7) << 4;
      bf16x8 kb0 = *reinterpret_cast<const bf16x8*>(Kb + row * 128 + ((lg * 16) ^ sw));
      bf16x8 kb1 = *reinterpret_cast<const bf16x8*>(Kb + row * 128 + ((lg * 16 + 64) ^ sw));
      s[nt] = MFMA16(qa0, kb0, s[nt]);
      s[nt] = MFMA16(qa1, kb1, s[nt]);
    }

    // masking — replicate reference f32 arithmetic exactly
#pragma unroll
    for (int nt = 0; nt < 4; nt++) {
      const int kc = k0 + nt * 16 + lr;
      const bool pd = padI[kc] != 0;
#pragma unroll
      for (int i = 0; i < 4; i++) {
        float v = s[nt][i] * 0.125f;
        if (pd) v = NEGV;
        if (kc > qrow + i) v += NEGV;
        s[nt][i] = v;
      }
    }

    // row max (16-lane groups)
    float x[4];
#pragma unroll
    for (int i = 0; i < 4; i++) {
      float xx = fmaxf(fmaxf(s[0][i], s[1][i]), fmaxf(s[2][i], s[3][i]));
#pragma unroll
      for (int d = 1; d < 16; d <<= 1) xx = fmaxf(xx, __shfl_xor(xx, d, 64));
      x[i] = xx;
    }

    // tile skip: if every exp(s - m) underflows (<=1.1e-38), tile contributes
    // nothing representable: sum += ~0, o unchanged, m unchanged. Exact.
    bool sk = true;
#pragma unroll
    for (int i = 0; i < 4; i++) sk = sk && (x[i] <= m_[i] - 88.0f);
    if (!__all(sk)) {
      float scl[4];
#pragma unroll
      for (int i = 0; i < 4; i++) {
        const float mn = fmaxf(m_[i], x[i]);
        scl[i] = __expf(m_[i] - mn);
        m_[i] = mn;
      }
#pragma unroll
      for (int i = 0; i < 4; i++) {
        float a = 0.0f;
#pragma unroll
        for (int nt = 0; nt < 4; nt++) {
          const float p = __expf(s[nt][i] - m_[i]);
          s[nt][i] = p;
          a += p;
        }
#pragma unroll
        for (int d = 1; d < 16; d <<= 1) a += __shfl_xor(a, d, 64);
        ld_[i] = ld_[i] * scl[i] + a;
        o[0][i] *= scl[i]; o[1][i] *= scl[i]; o[2][i] *= scl[i]; o[3][i] *= scl[i];
      }

      // P -> per-wave LDS (swizzled write)
#pragma unroll
      for (int nt = 0; nt < 4; nt++)
#pragma unroll
        for (int i = 0; i < 4; i++) {
          const int prow = lg * 4 + i;
          *(bf16_t*)((char*)(Ps[w]) + prow * 128 + (((nt * 16 + lr) * 2) ^ ((prow & 7) << 4))) =
              (bf16_t)s[nt][i];
        }
      asm volatile("s_waitcnt lgkmcnt(0)" ::: "memory");
      __builtin_amdgcn_sched_barrier(0);

      // PV: o[q,d] += P[q,k] * V[k,d]
      const int psw = (lr & 7) << 4;
#pragma unroll
      for (int c = 0; c < 2; c++) {
        bf16x8 pf = *reinterpret_cast<const bf16x8*>((char*)(Ps[w]) + lr * 128 + ((c * 64 + lg * 16) ^ psw));
#pragma unroll
        for (int nt = 0; nt < 4; nt++) {
          const int vrow = nt * 16 + lr;
          const int vsw = (vrow & 7) << 4;
          bf16x8 vf = *reinterpret_cast<const bf16x8*>(Vb + vrow * 128 + ((c * 64 + lg * 16) ^ vsw));
          o[nt] = MFMA16(pf, vf, o[nt]);
        }
      }
    }
    __builtin_amdgcn_s_barrier();  // protect buf[cur] before next prefetch overwrites
  }

  // epilogue: normalize and store bf16 [B,S,D]
#pragma unroll
  for (int nt = 0; nt < 4; nt++)
#pragma unroll
    for (int i = 0; i < 4; i++) {
      const float v = o[nt][i] / ld_[i];
      outp[(size_t)(b * 1024 + qrow + i) * 1024 + h * 64 + nt * 16 + lr] = (bf16_t)v;
    }
}

// ---------------------------------------------------------------------------
extern "C" void kernel_launch(void* const* d_in, const int* in_sizes, int n_in,
                              void* d_out, int out_size, void* d_ws, size_t ws_size,
                              hipStream_t stream) {
  const float* q   = (const float*)d_in[0];
  const float* k   = (const float*)d_in[1];
  const float* v   = (const float*)d_in[2];
  const int*   pad = (const int*)d_in[3];
  const float* wq  = (const float*)d_in[5];
  const float* bq  = (const float*)d_in[6];
  const float* wk  = (const float*)d_in[7];
  const float* wv  = (const float*)d_in[8];
  const float* bv  = (const float*)d_in[9];
  const float* wo  = (const float*)d_in[10];
  const float* bo  = (const float*)d_in[11];

  const int M = 8192, N = 1024, K = 1024;
  const int nBig = M * N;
  const int nW   = N * K;

  char* ws = (char*)d_ws;
  const size_t MiB = 1024 * 1024;
  bf16_t* qbf = (bf16_t*)(ws + 0 * MiB);
  bf16_t* kbf = (bf16_t*)(ws + 16 * MiB);
  bf16_t* vbf = (bf16_t*)(ws + 32 * MiB);
  bf16_t* qp  = (bf16_t*)(ws + 48 * MiB);
  bf16_t* kp  = (bf16_t*)(ws + 64 * MiB);
  bf16_t* vtw = (bf16_t*)(ws + 80 * MiB);
  bf16_t* wqb = (bf16_t*)(ws + 96 * MiB);
  bf16_t* wkb = (bf16_t*)(ws + 98 * MiB);
  bf16_t* wvb = (bf16_t*)(ws + 100 * MiB);
  bf16_t* wob = (bf16_t*)(ws + 102 * MiB);
  bf16_t* attnO = qbf;  // qbf dead after q-projection

  cvt_qkv<<<dim3(nBig / 2048, 3), 256, 0, stream>>>(q, k, v, qbf, kbf, vbf, nBig / 8);
  cvt_w4 <<<dim3(nW / 2048, 4), 256, 0, stream>>>(wq, wk, wv, wo, wqb, wkb, wvb, wob, nW / 8);

  dim3 gg(N / 128, M / 128);
  gemm_bt<0, true ><<<gg, 256, 0, stream>>>(qbf, wqb, bq, qp,  M, N, K);
  gemm_bt<0, false><<<gg, 256, 0, stream>>>(kbf, wkb, nullptr, kp, M, N, K);
  gemm_bt<1, true ><<<gg, 256, 0, stream>>>(vbf, wvb, bv, vtw, M, N, K);

  attn_fused<<<2048, 256, 0, stream>>>(qp, kp, vtw, pad, attnO);

  gemm_bt<2, true ><<<gg, 256, 0, stream>>>(attnO, wob, bo, d_out, M, N, K);
}

// Round 3
// 231.394 us; speedup vs baseline: 1.3451x; 1.1884x over previous
//
#include <hip/hip_runtime.h>
#include <hip/hip_bf16.h>
#include <cstdint>
#include <math.h>

// ---------------------------------------------------------------------------
// MyMultiHeadAttention: q/k/v proj (bf16 MFMA GEMM) -> fused flash attention
// (swapped QK^T, in-register softmax+P, causal truncation, exact -1e9 mask
// semantics) -> output proj (f32 out).  B=8 S=1024 D=1024 H=16 Dh=64.
// ---------------------------------------------------------------------------

typedef __bf16 bf16_t;
typedef __bf16 bf16x8 __attribute__((ext_vector_type(8)));
typedef __bf16 bf16x4 __attribute__((ext_vector_type(4)));
typedef float  f32x4  __attribute__((ext_vector_type(4)));

#define MFMA16(a, b, c) __builtin_amdgcn_mfma_f32_16x16x32_bf16((a), (b), (c), 0, 0, 0)
#define NEGV (-1e9f)

__device__ __forceinline__ void gl_lds16(const void* gp, void* lp) {
  __builtin_amdgcn_global_load_lds(
      (__attribute__((address_space(1))) void*)(gp),
      (__attribute__((address_space(3))) void*)(lp), 16, 0, 0);
}

__device__ __forceinline__ unsigned int pk2(float lo, float hi) {
  unsigned short a = __builtin_bit_cast(unsigned short, (bf16_t)lo);
  unsigned short b = __builtin_bit_cast(unsigned short, (bf16_t)hi);
  return (unsigned int)a | ((unsigned int)b << 16);
}

// ---------------- f32 -> bf16 bulk converts (8 elems/thread) ----------------
__device__ __forceinline__ void cvt_body(const float* __restrict__ in,
                                         bf16_t* __restrict__ out, int i, int n8) {
  if (i < n8) {
    const float4* p = reinterpret_cast<const float4*>(in) + (size_t)i * 2;
    float4 a = p[0], b = p[1];
    bf16x8 r = {(bf16_t)a.x, (bf16_t)a.y, (bf16_t)a.z, (bf16_t)a.w,
                (bf16_t)b.x, (bf16_t)b.y, (bf16_t)b.z, (bf16_t)b.w};
    *reinterpret_cast<bf16x8*>(out + (size_t)i * 8) = r;
  }
}

__global__ __launch_bounds__(256) void cvt_qkv(const float* __restrict__ a, const float* __restrict__ b,
                                               const float* __restrict__ c,
                                               bf16_t* __restrict__ oa, bf16_t* __restrict__ ob,
                                               bf16_t* __restrict__ oc, int n8) {
  const float* in = blockIdx.y == 0 ? a : (blockIdx.y == 1 ? b : c);
  bf16_t* out     = blockIdx.y == 0 ? oa : (blockIdx.y == 1 ? ob : oc);
  cvt_body(in, out, blockIdx.x * 256 + threadIdx.x, n8);
}

__global__ __launch_bounds__(256) void cvt_w4(const float* __restrict__ a, const float* __restrict__ b,
                                              const float* __restrict__ c, const float* __restrict__ d,
                                              bf16_t* __restrict__ oa, bf16_t* __restrict__ ob,
                                              bf16_t* __restrict__ oc, bf16_t* __restrict__ od, int n8) {
  const float* in = blockIdx.y == 0 ? a : (blockIdx.y == 1 ? b : (blockIdx.y == 2 ? c : d));
  bf16_t* out     = blockIdx.y == 0 ? oa : (blockIdx.y == 1 ? ob : (blockIdx.y == 2 ? oc : od));
  cvt_body(in, out, blockIdx.x * 256 + threadIdx.x, n8);
}

// ---------------- GEMM: C[m,n] = sum_k A[m,k]*W[n,k] (+bias) ----------------
// MODE 0: out bf16 [M,N].  MODE 1: out bf16 vt[b,h,d,s].  MODE 2: out f32.
template <int MODE, bool BIAS>
__global__ __launch_bounds__(256) void gemm_bt(const bf16_t* __restrict__ A,
                                               const bf16_t* __restrict__ W,
                                               const float* __restrict__ bias,
                                               void* __restrict__ outp,
                                               int M, int N, int K) {
  __shared__ bf16_t As[128 * 32];
  __shared__ bf16_t Bs[128 * 32];
  const int t = threadIdx.x;
  const int w = t >> 6, l = t & 63, lr = l & 15, lg = l >> 4;
  const int m0 = blockIdx.y * 128, n0 = blockIdx.x * 128;
  const int wm = (w >> 1) * 64, wn = (w & 1) * 64;

  f32x4 acc[4][4] = {};
  const bf16_t* Ag = A + (size_t)(m0 + (t >> 2)) * K + (t & 3) * 8;
  const bf16_t* Wg = W + (size_t)(n0 + (t >> 2)) * K + (t & 3) * 8;
  char* AsB = (char*)As;
  char* BsB = (char*)Bs;

  for (int kt = 0; kt < K; kt += 32) {
    gl_lds16(Ag + kt,                    AsB + t * 16);
    gl_lds16(Ag + kt + (size_t)64 * K,   AsB + 4096 + t * 16);
    gl_lds16(Wg + kt,                    BsB + t * 16);
    gl_lds16(Wg + kt + (size_t)64 * K,   BsB + 4096 + t * 16);
    asm volatile("s_waitcnt vmcnt(0)");
    __syncthreads();

    bf16x8 af[4], bfr[4];
#pragma unroll
    for (int mt = 0; mt < 4; mt++)
      af[mt] = *reinterpret_cast<const bf16x8*>(AsB + ((wm + mt * 16 + lr) * 32 + lg * 8) * 2);
#pragma unroll
    for (int nt = 0; nt < 4; nt++)
      bfr[nt] = *reinterpret_cast<const bf16x8*>(BsB + ((wn + nt * 16 + lr) * 32 + lg * 8) * 2);
#pragma unroll
    for (int mt = 0; mt < 4; mt++)
#pragma unroll
      for (int nt = 0; nt < 4; nt++)
        acc[mt][nt] = MFMA16(af[mt], bfr[nt], acc[mt][nt]);
    __syncthreads();
  }

#pragma unroll
  for (int nt = 0; nt < 4; nt++) {
    const int col = n0 + wn + nt * 16 + lr;
    const float bb = BIAS ? bias[col] : 0.0f;
#pragma unroll
    for (int mt = 0; mt < 4; mt++) {
#pragma unroll
      for (int i = 0; i < 4; i++) {
        const int row = m0 + wm + mt * 16 + lg * 4 + i;
        const float v = acc[mt][nt][i] + bb;
        if (MODE == 2) {
          ((float*)outp)[(size_t)row * N + col] = v;
        } else if (MODE == 0) {
          ((bf16_t*)outp)[(size_t)row * N + col] = (bf16_t)v;
        } else {  // vt[( (b*16+h)*64 + d )*1024 + s]
          const int b = row >> 10, s = row & 1023;
          const int h = col >> 6, d = col & 63;
          ((bf16_t*)outp)[(size_t)((b * 16 + h) * 64 + d) * 1024 + s] = (bf16_t)v;
        }
      }
    }
  }
}

// ---------------- fused flash attention (swapped / in-register) ----------------
// Grid 2048 (XCD-swizzled). 256 thr = 4 waves, 16 q-rows/wave.
// S^T trick: s = mfma(Kfrag, Qfrag) -> lane holds 16 keys of ONE q (q = lane&15).
// P redistributed in-register (pack bf16 + shfl butterfly), PV = mfma(Vt, P^T).
// Causal truncation: q-tile j runs j+1 k-tiles when no degenerate row possible
// (exactness argument: fully-future tiles give exp(<= -1e9+40 - m_ + 1e3) == 0
// in f32, identical to the reference's underflow).
__global__ __launch_bounds__(256) void attn_fused(const bf16_t* __restrict__ qp,
                                                  const bf16_t* __restrict__ kp,
                                                  const bf16_t* __restrict__ vt,
                                                  const int* __restrict__ pad,
                                                  bf16_t* __restrict__ outp) {
  __shared__ bf16_t Ks[2][64 * 64];   // [key][dh], XOR-swizzled
  __shared__ bf16_t Vts[2][64 * 64];  // [dh][key], XOR-swizzled
  __shared__ int padI[1024];
  __shared__ int sf[4];
  const int t = threadIdx.x, w = t >> 6, l = t & 63, lr = l & 15, lg = l >> 4;
  const int wg = (int)(blockIdx.x & 7) * 256 + (int)(blockIdx.x >> 3);
  const int bh = wg >> 4, b = bh >> 4, h = bh & 15;
  const int q0 = (wg & 15) * 64;

  const int srow = t >> 3, sc = t & 7;
  const int gc = sc ^ (srow & 7);  // pre-swizzled global chunk
  const bf16_t* kgb = kp + (size_t)(b * 1024 + srow) * 1024 + h * 64 + gc * 8;
  const bf16_t* vgb = vt + (size_t)(bh * 64 + srow) * 1024 + gc * 8;

  auto stage = [&](int bufi, int k0s) {
    char* Kd = (char*)(Ks[bufi]);
    char* Vd = (char*)(Vts[bufi]);
    gl_lds16(kgb + (size_t)k0s * 1024,        Kd + t * 16);
    gl_lds16(kgb + (size_t)(k0s + 32) * 1024, Kd + 4096 + t * 16);
    gl_lds16(vgb + k0s,                       Vd + t * 16);
    gl_lds16(vgb + k0s + (size_t)32 * 1024,   Vd + 4096 + t * 16);
  };

  // degenerate-row check: any unpadded key in [0, q0]?
  bool un = false;
  for (int j = t; j <= q0; j += 256) un |= (pad[b * 1024 + j] == 0);
  const bool anyun = __any(un);
  if (l == 0) sf[w] = anyun ? 1 : 0;

  stage(0, 0);
  gl_lds16(pad + b * 1024 + t * 4, (char*)padI + t * 16);

  // Q fragments (B-operand: col = q-row = lr, k = dh)
  const bf16_t* qg = qp + (size_t)(b * 1024 + q0 + w * 16 + lr) * 1024 + h * 64 + lg * 8;
  const bf16x8 qa0 = *reinterpret_cast<const bf16x8*>(qg);
  const bf16x8 qa1 = *reinterpret_cast<const bf16x8*>(qg + 32);

  __syncthreads();  // sf ready; also drains tile-0 staging (prologue only)
  const int ktEnd = (sf[0] | sf[1] | sf[2] | sf[3]) ? ((q0 >> 6) + 1) : 16;

  f32x4 o[4] = {};
  float m_ = -INFINITY, ld_ = 0.0f;
  const int qrow_l = q0 + w * 16 + lr;  // this lane's q row

  for (int kt = 0; kt < ktEnd; ++kt) {
    const int cur = kt & 1;
    if (kt + 1 < ktEnd) {
      stage(cur ^ 1, (kt + 1) * 64);
      asm volatile("s_waitcnt vmcnt(4)" ::: "memory");
    } else {
      asm volatile("s_waitcnt vmcnt(0)" ::: "memory");
    }
    __builtin_amdgcn_s_barrier();

    const char* Kb = (const char*)(Ks[cur]);
    const char* Vb = (const char*)(Vts[cur]);
    const int k0 = kt * 64;

    // S^T = K * Q^T : s[nt][i] = score[key = k0+nt*16+lg*4+i][q = qrow_l]
    f32x4 s[4] = {};
#pragma unroll
    for (int nt = 0; nt < 4; nt++) {
      const int row = nt * 16 + lr;
      const int sw = (row & 7) << 4;
      bf16x8 kb0 = *reinterpret_cast<const bf16x8*>(Kb + row * 128 + ((lg * 16) ^ sw));
      bf16x8 kb1 = *reinterpret_cast<const bf16x8*>(Kb + row * 128 + ((lg * 16 + 64) ^ sw));
      s[nt] = MFMA16(kb0, qa0, s[nt]);
      s[nt] = MFMA16(kb1, qa1, s[nt]);
    }

    // masking — reference f32 arithmetic exactly
    const bool needc = (k0 + 63 > q0);  // tile touches/crosses the diagonal
#pragma unroll
    for (int nt = 0; nt < 4; nt++) {
      const int kc4 = k0 + nt * 16 + lg * 4;
      const int4 pd = *reinterpret_cast<const int4*>(&padI[kc4]);
      const int pdv[4] = {pd.x, pd.y, pd.z, pd.w};
#pragma unroll
      for (int i = 0; i < 4; i++) {
        float v = s[nt][i] * 0.125f;
        if (pdv[i]) v = NEGV;
        if (needc && (kc4 + i > qrow_l)) v += NEGV;
        s[nt][i] = v;
      }
    }

    // row max: 15 reg-local fmax + 2 shfl
    float mx = s[0][0];
#pragma unroll
    for (int nt = 0; nt < 4; nt++)
#pragma unroll
      for (int i = 0; i < 4; i++) mx = fmaxf(mx, s[nt][i]);
    mx = fmaxf(mx, __shfl_xor(mx, 16, 64));
    mx = fmaxf(mx, __shfl_xor(mx, 32, 64));

    if (!__all(mx <= m_ - 88.0f)) {          // dynamic underflow skip
      if (!__all(mx <= m_ + 8.0f)) {         // defer-max: rescale only when needed
        const float mn = fmaxf(m_, mx);
        const float scl = __expf(m_ - mn);
        m_ = mn;
        ld_ *= scl;
#pragma unroll
        for (int nt = 0; nt < 4; nt++) o[nt] *= scl;
      }
      // exp + row sum
      float a = 0.0f;
#pragma unroll
      for (int nt = 0; nt < 4; nt++)
#pragma unroll
        for (int i = 0; i < 4; i++) {
          const float p = __expf(s[nt][i] - m_);
          s[nt][i] = p;
          a += p;
        }
      a += __shfl_xor(a, 16, 64);
      a += __shfl_xor(a, 32, 64);
      ld_ += a;

      // pack P^T to bf16 pairs: u[nt][k] covers keys nt*16+lg*4+{2k,2k+1}
      unsigned int u[4][2], sh[4][2];
#pragma unroll
      for (int nt = 0; nt < 4; nt++) {
        u[nt][0] = pk2(s[nt][0], s[nt][1]);
        u[nt][1] = pk2(s[nt][2], s[nt][3]);
      }
      // butterfly round 1: xor16 partner's data
#pragma unroll
      for (int nt = 0; nt < 4; nt++) {
        sh[nt][0] = (unsigned int)__shfl_xor((int)u[nt][0], 16, 64);
        sh[nt][1] = (unsigned int)__shfl_xor((int)u[nt][1], 16, 64);
      }
      const bool ev = (lg & 1) == 0;
      unsigned int Y[8];
      Y[0] = ev ? u[0][0] : sh[1][0];  Y[1] = ev ? u[0][1] : sh[1][1];
      Y[2] = ev ? u[2][0] : sh[3][0];  Y[3] = ev ? u[2][1] : sh[3][1];
      Y[4] = ev ? sh[0][0] : u[1][0];  Y[5] = ev ? sh[0][1] : u[1][1];
      Y[6] = ev ? sh[2][0] : u[3][0];  Y[7] = ev ? sh[2][1] : u[3][1];
      // butterfly round 2: lanes lg==1,2 swap full payload (xor48)
      const bool mid = (lg == 1) || (lg == 2);
#pragma unroll
      for (int j = 0; j < 8; j++) {
        const unsigned int z = (unsigned int)__shfl_xor((int)Y[j], 48, 64);
        Y[j] = mid ? z : Y[j];
      }
      union U8 { unsigned int u[4]; bf16x8 v; };
      U8 pb0, pb1;
      pb0.u[0] = Y[0]; pb0.u[1] = Y[1]; pb0.u[2] = Y[4]; pb0.u[3] = Y[5];
      pb1.u[0] = Y[2]; pb1.u[1] = Y[3]; pb1.u[2] = Y[6]; pb1.u[3] = Y[7];

      // PV: O^T[d][q] += V^T[d][k] * P^T[k][q]
#pragma unroll
      for (int nt = 0; nt < 4; nt++) {
        const int vrow = nt * 16 + lr;
        const int vsw = (vrow & 7) << 4;
        bf16x8 vf0 = *reinterpret_cast<const bf16x8*>(Vb + vrow * 128 + ((lg * 16) ^ vsw));
        bf16x8 vf1 = *reinterpret_cast<const bf16x8*>(Vb + vrow * 128 + ((64 + lg * 16) ^ vsw));
        o[nt] = MFMA16(vf0, pb0.v, o[nt]);
        o[nt] = MFMA16(vf1, pb1.v, o[nt]);
      }
    }
    __builtin_amdgcn_s_barrier();  // protect buf[cur] before next prefetch
  }

  // epilogue: o^T[d = nt*16+lg*4+i][q = lr], normalize, vector store 8B
  const float rinv = 1.0f / ld_;
#pragma unroll
  for (int nt = 0; nt < 4; nt++) {
    bf16x4 r = {(bf16_t)(o[nt][0] * rinv), (bf16_t)(o[nt][1] * rinv),
                (bf16_t)(o[nt][2] * rinv), (bf16_t)(o[nt][3] * rinv)};
    *reinterpret_cast<bf16x4*>(outp + (size_t)(b * 1024 + qrow_l) * 1024 + h * 64 + nt * 16 + lg * 4) = r;
  }
}

// ---------------------------------------------------------------------------
extern "C" void kernel_launch(void* const* d_in, const int* in_sizes, int n_in,
                              void* d_out, int out_size, void* d_ws, size_t ws_size,
                              hipStream_t stream) {
  const float* q   = (const float*)d_in[0];
  const float* k   = (const float*)d_in[1];
  const float* v   = (const float*)d_in[2];
  const int*   pad = (const int*)d_in[3];
  const float* wq  = (const float*)d_in[5];
  const float* bq  = (const float*)d_in[6];
  const float* wk  = (const float*)d_in[7];
  const float* wv  = (const float*)d_in[8];
  const float* bv  = (const float*)d_in[9];
  const float* wo  = (const float*)d_in[10];
  const float* bo  = (const float*)d_in[11];

  const int M = 8192, N = 1024, K = 1024;
  const int nBig = M * N;
  const int nW   = N * K;

  char* ws = (char*)d_ws;
  const size_t MiB = 1024 * 1024;
  bf16_t* qbf = (bf16_t*)(ws + 0 * MiB);
  bf16_t* kbf = (bf16_t*)(ws + 16 * MiB);
  bf16_t* vbf = (bf16_t*)(ws + 32 * MiB);
  bf16_t* qp  = (bf16_t*)(ws + 48 * MiB);
  bf16_t* kp  = (bf16_t*)(ws + 64 * MiB);
  bf16_t* vtw = (bf16_t*)(ws + 80 * MiB);
  bf16_t* wqb = (bf16_t*)(ws + 96 * MiB);
  bf16_t* wkb = (bf16_t*)(ws + 98 * MiB);
  bf16_t* wvb = (bf16_t*)(ws + 100 * MiB);
  bf16_t* wob = (bf16_t*)(ws + 102 * MiB);
  bf16_t* attnO = qbf;  // qbf dead after q-projection

  cvt_qkv<<<dim3(nBig / 2048, 3), 256, 0, stream>>>(q, k, v, qbf, kbf, vbf, nBig / 8);
  cvt_w4 <<<dim3(nW / 2048, 4), 256, 0, stream>>>(wq, wk, wv, wo, wqb, wkb, wvb, wob, nW / 8);

  dim3 gg(N / 128, M / 128);
  gemm_bt<0, true ><<<gg, 256, 0, stream>>>(qbf, wqb, bq, qp,  M, N, K);
  gemm_bt<0, false><<<gg, 256, 0, stream>>>(kbf, wkb, nullptr, kp, M, N, K);
  gemm_bt<1, true ><<<gg, 256, 0, stream>>>(vbf, wvb, bv, vtw, M, N, K);

  attn_fused<<<2048, 256, 0, stream>>>(qp, kp, vtw, pad, attnO);

  gemm_bt<2, true ><<<gg, 256, 0, stream>>>(attnO, wob, bo, d_out, M, N, K);
}